// Round 4
// baseline (292.716 us; speedup 1.0000x reference)
//
#include <hip/hip_runtime.h>

#define NPIX 16384

typedef _Float16 f16;
typedef __attribute__((ext_vector_type(8))) _Float16 half8;
typedef __attribute__((ext_vector_type(8))) unsigned short ushort8;
typedef __attribute__((ext_vector_type(4))) float f32x4;   // native vec4 (nontemporal-compatible)

// Load 8 consecutive floats (nontemporal), convert to half8 fragment.
__device__ inline half8 cvt8_nt(const float* __restrict__ p) {
  f32x4 a = __builtin_nontemporal_load((const f32x4*)p);
  f32x4 b = __builtin_nontemporal_load((const f32x4*)p + 1);
  half8 r;
  r[0] = (f16)a.x; r[1] = (f16)a.y; r[2] = (f16)a.z; r[3] = (f16)a.w;
  r[4] = (f16)b.x; r[5] = (f16)b.y; r[6] = (f16)b.z; r[7] = (f16)b.w;
  return r;
}
__device__ inline half8 cvt8(const float* __restrict__ p) {
  f32x4 a = *(const f32x4*)p;
  f32x4 b = *(const f32x4*)(p + 4);
  half8 r;
  r[0] = (f16)a.x; r[1] = (f16)a.y; r[2] = (f16)a.z; r[3] = (f16)a.w;
  r[4] = (f16)b.x; r[5] = (f16)b.y; r[6] = (f16)b.z; r[7] = (f16)b.w;
  return r;
}

// Transpose+convert: y [16][8][NPIX] f32 + noise [16][8][NPIX] f32
//   -> feats[p][b][n] f16 ([NPIX][256], 8 MB in d_ws)
// One block = 64 consecutive pixels x all 256 (b,n) planes.
// Reads: 256B contiguous per plane (coalesced). Writes: 32KB contiguous per block.
__global__ __launch_bounds__(256) void pack_feats(
    const float* __restrict__ y,
    const float* __restrict__ nz,
    f16* __restrict__ out)
{
  __shared__ f16 tile[64][258];  // [px][plane], odd-dword row stride -> conflict-free
  const int p0 = blockIdx.x << 6;
  const int t = threadIdx.x;
  const int lane16 = t & 15;
  const int pl0 = t >> 4;
  #pragma unroll
  for (int g = 0; g < 16; ++g) {
    const int plane = g * 16 + pl0;          // plane = b*16 + n
    const int b = plane >> 4, n = plane & 15;
    const float* src = (n < 8) ? (y + (b * 8 + n) * NPIX)
                               : (nz + (b * 8 + (n - 8)) * NPIX);
    f32x4 v = __builtin_nontemporal_load((const f32x4*)(src + p0 + lane16 * 4));
    tile[lane16 * 4 + 0][plane] = (f16)v.x;
    tile[lane16 * 4 + 1][plane] = (f16)v.y;
    tile[lane16 * 4 + 2][plane] = (f16)v.z;
    tile[lane16 * 4 + 3][plane] = (f16)v.w;
  }
  __syncthreads();
  // 64 px * 512B = 32KB out, fully coalesced: 8 iters x 256 lanes x 16B
  #pragma unroll
  for (int it = 0; it < 8; ++it) {
    const int idx = it * 256 + t;
    const int px = idx >> 5;       // 32 x 16B chunks per pixel
    const int c = idx & 31;
    ushort8 v = *(const ushort8*)&tile[px][c * 8];
    *(ushort8*)(out + (p0 + px) * 256 + c * 8) = v;  // keep cached: re-read by lr_main
  }
}

// One wave per pixel, 4 waves/block.
// einsum: D[b][m] = sum_{k,n} feats[b][nb(p,k)][n] * wmap[p][k][m][n]  (K=144 pad 160)
// MFMA f32_16x16x32_f16: A[i=lane&15][k=q*8+j], B[j=lane&15][k], D: col=lane&15, row=q*4+r.
__global__ __launch_bounds__(256) void lr_main(
    const f16*  __restrict__ feats,   // [NPIX][16][16] f16 (ws)
    const float* __restrict__ wmap,   // [NPIX][9][16][16] f32
    const float* __restrict__ noise2, // [16][NPIX][8] f32
    const float* __restrict__ w1,     // [64][24] f32
    const float* __restrict__ b1,     // [64] f32
    const float* __restrict__ w2,     // [8][64] f32
    const float* __restrict__ b2,     // [8] f32
    const int*  __restrict__ nidx,    // [NPIX][9] i32
    float* __restrict__ outp)         // [16][8][NPIX] f32
{
  __shared__ f16 lds_i[4][16 * 24];  // per-wave intermediate [b][m], stride 24 (48B)
  __shared__ f16 lds_h[4][16 * 72];  // per-wave h [b][j], stride 72 (144B)

  const int t = threadIdx.x;
  const int wv = t >> 6;
  const int l = t & 63;
  const int col = l & 15;
  const int q = l >> 4;
  const int p = (blockIdx.x << 2) + wv;

  f16* li = lds_i[wv];
  f16* lh = lds_h[wv];

  const int n0 = (q & 1) * 8;   // n-half within the 32-wide k-chunk
  const int kh = q >> 1;        // which of the chunk's two k's

  // Prefetch all neighbor indices up front (shortens gather dependency chain).
  const int* nrow = nidx + p * 9;
  int nb[9];
  #pragma unroll
  for (int k = 0; k < 9; ++k) nb[k] = nrow[k];

  // Prefetch this wave's noise2 slice early (independent of einsum).
  half8 amlp = {0, 0, 0, 0, 0, 0, 0, 0};
  if (q == 2) {
    const float* n2p = noise2 + (col * NPIX + p) * 8;
    f32x4 a = __builtin_nontemporal_load((const f32x4*)n2p);
    f32x4 b = __builtin_nontemporal_load((const f32x4*)n2p + 1);
    amlp[0] = (f16)a.x; amlp[1] = (f16)a.y; amlp[2] = (f16)a.z; amlp[3] = (f16)a.w;
    amlp[4] = (f16)b.x; amlp[5] = (f16)b.y; amlp[6] = (f16)b.z; amlp[7] = (f16)b.w;
  }

  // ---- einsum: 5 MFMAs over kk = (k,n), padded 144 -> 160 ----
  f32x4 acc = {0.f, 0.f, 0.f, 0.f};
  #pragma unroll
  for (int c = 0; c < 4; ++c) {
    const int k = 2 * c + kh;
    half8 a = *(const half8*)(feats + nb[k] * 256 + col * 16 + n0);  // cached (L1/L2)
    half8 bf = cvt8_nt(wmap + ((p * 9 + k) * 16 + col) * 16 + n0);   // streaming, nt
    acc = __builtin_amdgcn_mfma_f32_16x16x32_f16(a, bf, acc, 0, 0, 0);
  }
  {
    half8 a = {0, 0, 0, 0, 0, 0, 0, 0};
    half8 bf = {0, 0, 0, 0, 0, 0, 0, 0};
    if (q < 2) {  // kk 128..143 (k=8); 144..159 zero pad
      a = *(const half8*)(feats + nb[8] * 256 + col * 16 + n0);
      bf = cvt8_nt(wmap + ((p * 9 + 8) * 16 + col) * 16 + n0);
    }
    acc = __builtin_amdgcn_mfma_f32_16x16x32_f16(a, bf, acc, 0, 0, 0);
  }

  // intermediate D[b=q*4+r][m=col] -> LDS (f16) for A-layout re-read
  #pragma unroll
  for (int r = 0; r < 4; ++r) {
    li[(q * 4 + r) * 24 + col] = (f16)acc[r];
  }
  __syncthreads();

  // ---- MLP1: h[b][j] = relu(mlp_in[b][0..23] . w1[j][:] + b1[j]); K=24 pad 32, N=64 ----
  if (q < 2) amlp = *(const half8*)(li + col * 24 + q * 8);  // d 0..15: intermediate
  // q==2: noise2 (prefetched); q==3: zero pad

  const f32x4 zero4 = {0.f, 0.f, 0.f, 0.f};
  #pragma unroll
  for (int jc = 0; jc < 4; ++jc) {
    half8 wf = {0, 0, 0, 0, 0, 0, 0, 0};
    if (q < 3) wf = cvt8(w1 + (jc * 16 + col) * 24 + q * 8);   // tiny, cached
    f32x4 h4 = __builtin_amdgcn_mfma_f32_16x16x32_f16(amlp, wf, zero4, 0, 0, 0);
    const float b1f = b1[jc * 16 + col];
    #pragma unroll
    for (int r = 0; r < 4; ++r) {
      float hv = fmaxf(h4[r] + b1f, 0.f);
      lh[(q * 4 + r) * 72 + jc * 16 + col] = (f16)hv;
    }
  }
  __syncthreads();

  // ---- MLP2: out[b][f] = h[b][:] . w2[f][:] + b2[f]; K=64, N=8 pad 16 ----
  f32x4 oacc = {0.f, 0.f, 0.f, 0.f};
  #pragma unroll
  for (int c2 = 0; c2 < 2; ++c2) {
    half8 a2 = *(const half8*)(lh + col * 72 + c2 * 32 + q * 8);
    half8 wf = {0, 0, 0, 0, 0, 0, 0, 0};
    if (col < 8) wf = cvt8(w2 + col * 64 + c2 * 32 + q * 8);   // tiny, cached
    oacc = __builtin_amdgcn_mfma_f32_16x16x32_f16(a2, wf, oacc, 0, 0, 0);
  }
  if (col < 8) {
    const float b2f = b2[col];
    #pragma unroll
    for (int r = 0; r < 4; ++r) {
      const int b = q * 4 + r;
      __builtin_nontemporal_store(oacc[r] + b2f, outp + (b * 8 + col) * NPIX + p);
    }
  }
}

extern "C" void kernel_launch(void* const* d_in, const int* in_sizes, int n_in,
                              void* d_out, int out_size, void* d_ws, size_t ws_size,
                              hipStream_t stream) {
  const float* y    = (const float*)d_in[0];
  const float* nz   = (const float*)d_in[1];
  const float* nz2  = (const float*)d_in[2];
  const float* wmap = (const float*)d_in[3];
  const float* w1   = (const float*)d_in[4];
  const float* b1   = (const float*)d_in[5];
  const float* w2   = (const float*)d_in[6];
  const float* b2   = (const float*)d_in[7];
  const int* nidx   = (const int*)d_in[8];
  float* outp = (float*)d_out;
  f16* feats  = (f16*)d_ws;   // 8 MB scratch: feats[NPIX][16][16] f16

  hipLaunchKernelGGL(pack_feats, dim3(NPIX / 64), dim3(256), 0, stream,
                     y, nz, feats);
  hipLaunchKernelGGL(lr_main, dim3(NPIX / 4), dim3(256), 0, stream,
                     feats, wmap, nz2, w1, b1, w2, b2, nidx, outp);
}

// Round 6
// 275.689 us; speedup vs baseline: 1.0618x; 1.0618x over previous
//
#include <hip/hip_runtime.h>

#define NPIX 16384

typedef _Float16 f16;
typedef __attribute__((ext_vector_type(8))) _Float16 half8;
typedef __attribute__((ext_vector_type(8))) unsigned short ushort8;
typedef __attribute__((ext_vector_type(4))) float f32x4;   // native vec4

// Load 8 consecutive floats (nontemporal), convert to half8 fragment.
__device__ inline half8 cvt8_nt(const float* __restrict__ p) {
  f32x4 a = __builtin_nontemporal_load((const f32x4*)p);
  f32x4 b = __builtin_nontemporal_load((const f32x4*)p + 1);
  half8 r;
  r[0] = (f16)a.x; r[1] = (f16)a.y; r[2] = (f16)a.z; r[3] = (f16)a.w;
  r[4] = (f16)b.x; r[5] = (f16)b.y; r[6] = (f16)b.z; r[7] = (f16)b.w;
  return r;
}
__device__ inline half8 cvt8(const float* __restrict__ p) {
  f32x4 a = *(const f32x4*)p;
  f32x4 b = *(const f32x4*)(p + 4);
  half8 r;
  r[0] = (f16)a.x; r[1] = (f16)a.y; r[2] = (f16)a.z; r[3] = (f16)a.w;
  r[4] = (f16)b.x; r[5] = (f16)b.y; r[6] = (f16)b.z; r[7] = (f16)b.w;
  return r;
}

// Transpose+convert: y [16][8][NPIX] f32 + noise [16][8][NPIX] f32
//   -> feats[p][b][n] f16 ([NPIX][256], 8 MB in d_ws)
__global__ __launch_bounds__(256) void pack_feats(
    const float* __restrict__ y,
    const float* __restrict__ nz,
    f16* __restrict__ out)
{
  __shared__ f16 tile[64][258];
  const int p0 = blockIdx.x << 6;
  const int t = threadIdx.x;
  const int lane16 = t & 15;
  const int pl0 = t >> 4;
  #pragma unroll
  for (int g = 0; g < 16; ++g) {
    const int plane = g * 16 + pl0;          // plane = b*16 + n
    const int b = plane >> 4, n = plane & 15;
    const float* src = (n < 8) ? (y + (b * 8 + n) * NPIX)
                               : (nz + (b * 8 + (n - 8)) * NPIX);
    f32x4 v = __builtin_nontemporal_load((const f32x4*)(src + p0 + lane16 * 4));
    tile[lane16 * 4 + 0][plane] = (f16)v.x;
    tile[lane16 * 4 + 1][plane] = (f16)v.y;
    tile[lane16 * 4 + 2][plane] = (f16)v.z;
    tile[lane16 * 4 + 3][plane] = (f16)v.w;
  }
  __syncthreads();
  #pragma unroll
  for (int it = 0; it < 8; ++it) {
    const int idx = it * 256 + t;
    const int px = idx >> 5;
    const int c = idx & 31;
    ushort8 v = *(const ushort8*)&tile[px][c * 8];
    *(ushort8*)(out + (p0 + px) * 256 + c * 8) = v;  // cached: re-read by lr_main
  }
}

// 4 waves/block, each wave processes 4 consecutive pixels -> 16 px/block,
// grid NPIX/16 = 1024 = 4 blocks/CU (all pixels resident in one generation).
// XCD-swizzled: bid%8 = XCD (round-robin dispatch); XCD x owns a contiguous
// 2048-pixel slab -> L2-local feats gathers + write-combinable output lines.
// einsum: D[b][m] = sum_{k,n} feats[b][nb(p,k)][n] * wmap[p][k][m][n]  (K=144 pad 160)
// MFMA f32_16x16x32_f16: A[i=lane&15][k=q*8+j], B[j=lane&15][k], D: col=lane&15, row=q*4+r.
__global__ __launch_bounds__(256, 4) void lr_main(
    const f16*  __restrict__ feats,   // [NPIX][16][16] f16 (ws)
    const float* __restrict__ wmap,   // [NPIX][9][16][16] f32
    const float* __restrict__ noise2, // [16][NPIX][8] f32
    const float* __restrict__ w1,     // [64][24] f32
    const float* __restrict__ b1,     // [64] f32
    const float* __restrict__ w2,     // [8][64] f32
    const float* __restrict__ b2,     // [8] f32
    const int*  __restrict__ nidx,    // [NPIX][9] i32
    float* __restrict__ outp)         // [16][8][NPIX] f32
{
  __shared__ f16 lds_i[4][16 * 24];  // per-wave scratch: intermediate [b][m]
  __shared__ f16 lds_h[4][16 * 72];  // per-wave scratch: h [b][j]

  const int t = threadIdx.x;
  const int wv = t >> 6;
  const int l = t & 63;
  const int col = l & 15;
  const int q = l >> 4;

  const int bid = blockIdx.x;                      // [0, 1024)
  const int pw0 = (((bid & 7) << 7) + (bid >> 3)) * 16 + wv * 4;

  f16* li = lds_i[wv];
  f16* lh = lds_h[wv];

  const int n0 = (q & 1) * 8;
  const int kh = q >> 1;

  // ---- wave-uniform preloads (once per 4 pixels) ----
  // Neighbor indices are wave-uniform -> pin to SGPRs (saves ~36 VGPRs).
  int nb[4][9];
  #pragma unroll
  for (int px = 0; px < 4; ++px)
    #pragma unroll
    for (int k = 0; k < 9; ++k)
      nb[px][k] = __builtin_amdgcn_readfirstlane(nidx[(pw0 + px) * 9 + k]);

  half8 w1f[4];
  float b1f[4];
  #pragma unroll
  for (int jc = 0; jc < 4; ++jc) {
    w1f[jc] = (half8){0, 0, 0, 0, 0, 0, 0, 0};
    if (q < 3) w1f[jc] = cvt8(w1 + (jc * 16 + col) * 24 + q * 8);
    b1f[jc] = b1[jc * 16 + col];
  }
  half8 w2f[2] = {{0, 0, 0, 0, 0, 0, 0, 0}, {0, 0, 0, 0, 0, 0, 0, 0}};
  float b2f = 0.f;
  if (col < 8) {
    w2f[0] = cvt8(w2 + col * 64 + q * 8);
    w2f[1] = cvt8(w2 + col * 64 + 32 + q * 8);
    b2f = b2[col];
  }

  half8 n2f[4];
  #pragma unroll
  for (int px = 0; px < 4; ++px) {
    n2f[px] = (half8){0, 0, 0, 0, 0, 0, 0, 0};
    if (q == 2) n2f[px] = cvt8(noise2 + (col * NPIX + pw0 + px) * 8);
  }

  const f32x4 zero4 = {0.f, 0.f, 0.f, 0.f};

  for (int px = 0; px < 4; ++px) {
    const int p = pw0 + px;

    // ---- einsum: hoist ALL 10 fragments, then 5 MFMAs ----
    half8 af[5], bfr[5];
    #pragma unroll
    for (int c = 0; c < 4; ++c) {
      const int k = 2 * c + kh;
      af[c]  = *(const half8*)(feats + nb[px][k] * 256 + col * 16 + n0);
      bfr[c] = cvt8_nt(wmap + ((p * 9 + k) * 16 + col) * 16 + n0);
    }
    af[4]  = (half8){0, 0, 0, 0, 0, 0, 0, 0};
    bfr[4] = (half8){0, 0, 0, 0, 0, 0, 0, 0};
    if (q < 2) {  // kk 128..143 (k=8); 144..159 zero pad
      af[4]  = *(const half8*)(feats + nb[px][8] * 256 + col * 16 + n0);
      bfr[4] = cvt8_nt(wmap + ((p * 9 + 8) * 16 + col) * 16 + n0);
    }
    f32x4 acc = zero4;
    #pragma unroll
    for (int c = 0; c < 5; ++c)
      acc = __builtin_amdgcn_mfma_f32_16x16x32_f16(af[c], bfr[c], acc, 0, 0, 0);

    // intermediate D[b=q*4+r][m=col] -> wave-private LDS
    // (same-wave DS ops execute in issue order; no cross-wave sharing -> no barrier)
    #pragma unroll
    for (int r = 0; r < 4; ++r)
      li[(q * 4 + r) * 24 + col] = (f16)acc[r];

    // ---- MLP1: K=24 pad 32, N=64 ----
    half8 amlp = n2f[px];                                      // q==2: noise2; q==3: zero
    if (q < 2) amlp = *(const half8*)(li + col * 24 + q * 8);  // d 0..15: intermediate

    #pragma unroll
    for (int jc = 0; jc < 4; ++jc) {
      f32x4 h4 = __builtin_amdgcn_mfma_f32_16x16x32_f16(amlp, w1f[jc], zero4, 0, 0, 0);
      #pragma unroll
      for (int r = 0; r < 4; ++r) {
        float hv = fmaxf(h4[r] + b1f[jc], 0.f);
        lh[(q * 4 + r) * 72 + jc * 16 + col] = (f16)hv;
      }
    }

    // ---- MLP2: K=64, N=8 pad 16 ----
    f32x4 oacc = zero4;
    #pragma unroll
    for (int c2 = 0; c2 < 2; ++c2) {
      half8 a2 = *(const half8*)(lh + col * 72 + c2 * 32 + q * 8);
      oacc = __builtin_amdgcn_mfma_f32_16x16x32_f16(a2, w2f[c2], oacc, 0, 0, 0);
    }
    if (col < 8) {
      const float b2v = b2f;
      #pragma unroll
      for (int r = 0; r < 4; ++r) {
        const int b = q * 4 + r;
        outp[(b * 8 + col) * NPIX + p] = oacc[r] + b2v;  // regular store: L2 combines
      }
    }
  }
}

extern "C" void kernel_launch(void* const* d_in, const int* in_sizes, int n_in,
                              void* d_out, int out_size, void* d_ws, size_t ws_size,
                              hipStream_t stream) {
  const float* y    = (const float*)d_in[0];
  const float* nz   = (const float*)d_in[1];
  const float* nz2  = (const float*)d_in[2];
  const float* wmap = (const float*)d_in[3];
  const float* w1   = (const float*)d_in[4];
  const float* b1   = (const float*)d_in[5];
  const float* w2   = (const float*)d_in[6];
  const float* b2   = (const float*)d_in[7];
  const int* nidx   = (const int*)d_in[8];
  float* outp = (float*)d_out;
  f16* feats  = (f16*)d_ws;   // 8 MB scratch: feats[NPIX][16][16] f16

  hipLaunchKernelGGL(pack_feats, dim3(NPIX / 64), dim3(256), 0, stream,
                     y, nz, feats);
  hipLaunchKernelGGL(lr_main, dim3(NPIX / 16), dim3(256), 0, stream,
                     feats, wmap, nz2, w1, b1, w2, b2, nidx, outp);
}

// Round 7
// 261.765 us; speedup vs baseline: 1.1182x; 1.0532x over previous
//
#include <hip/hip_runtime.h>

#define NPIX 16384

typedef _Float16 f16;
typedef __attribute__((ext_vector_type(8))) _Float16 half8;
typedef __attribute__((ext_vector_type(8))) unsigned short ushort8;
typedef __attribute__((ext_vector_type(4))) float f32x4;   // native vec4

// Load 8 consecutive floats (nontemporal), convert to half8 fragment.
__device__ inline half8 cvt8_nt(const float* __restrict__ p) {
  f32x4 a = __builtin_nontemporal_load((const f32x4*)p);
  f32x4 b = __builtin_nontemporal_load((const f32x4*)p + 1);
  half8 r;
  r[0] = (f16)a.x; r[1] = (f16)a.y; r[2] = (f16)a.z; r[3] = (f16)a.w;
  r[4] = (f16)b.x; r[5] = (f16)b.y; r[6] = (f16)b.z; r[7] = (f16)b.w;
  return r;
}
__device__ inline half8 cvt8(const float* __restrict__ p) {
  f32x4 a = *(const f32x4*)p;
  f32x4 b = *(const f32x4*)(p + 4);
  half8 r;
  r[0] = (f16)a.x; r[1] = (f16)a.y; r[2] = (f16)a.z; r[3] = (f16)a.w;
  r[4] = (f16)b.x; r[5] = (f16)b.y; r[6] = (f16)b.z; r[7] = (f16)b.w;
  return r;
}

// Transpose+convert: y [16][8][NPIX] f32 + noise [16][8][NPIX] f32
//   -> feats[p][b][n] f16 ([NPIX][256], 8 MB in d_ws)
__global__ __launch_bounds__(256) void pack_feats(
    const float* __restrict__ y,
    const float* __restrict__ nz,
    f16* __restrict__ out)
{
  __shared__ f16 tile[64][258];
  const int p0 = blockIdx.x << 6;
  const int t = threadIdx.x;
  const int lane16 = t & 15;
  const int pl0 = t >> 4;
  #pragma unroll
  for (int g = 0; g < 16; ++g) {
    const int plane = g * 16 + pl0;          // plane = b*16 + n
    const int b = plane >> 4, n = plane & 15;
    const float* src = (n < 8) ? (y + (b * 8 + n) * NPIX)
                               : (nz + (b * 8 + (n - 8)) * NPIX);
    f32x4 v = __builtin_nontemporal_load((const f32x4*)(src + p0 + lane16 * 4));
    tile[lane16 * 4 + 0][plane] = (f16)v.x;
    tile[lane16 * 4 + 1][plane] = (f16)v.y;
    tile[lane16 * 4 + 2][plane] = (f16)v.z;
    tile[lane16 * 4 + 3][plane] = (f16)v.w;
  }
  __syncthreads();
  #pragma unroll
  for (int it = 0; it < 8; ++it) {
    const int idx = it * 256 + t;
    const int px = idx >> 5;
    const int c = idx & 31;
    ushort8 v = *(const ushort8*)&tile[px][c * 8];
    *(ushort8*)(out + (p0 + px) * 256 + c * 8) = v;  // cached: re-read by lr_main
  }
}

// 8 waves/block, 4 px/wave -> 32 consecutive pixels per block; grid NPIX/32 = 512.
// XCD swizzle: bid%8 = XCD; XCD x owns a contiguous 2048-pixel slab.
// Output is staged in LDS and written as FULL 128B lines (32 px * 4B per (b,f) row).
// einsum: D[b][m] = sum_{k,n} feats[b][nb(p,k)][n] * wmap[p][k][m][n]  (K=144 pad 160)
// MFMA f32_16x16x32_f16: A[i=lane&15][k=q*8+j], B[j=lane&15][k], D: col=lane&15, row=q*4+r.
__global__ __launch_bounds__(512, 4) void lr_main(
    const f16*  __restrict__ feats,   // [NPIX][16][16] f16 (ws)
    const float* __restrict__ wmap,   // [NPIX][9][16][16] f32
    const float* __restrict__ noise2, // [16][NPIX][8] f32
    const float* __restrict__ w1,     // [64][24] f32
    const float* __restrict__ b1,     // [64] f32
    const float* __restrict__ w2,     // [8][64] f32
    const float* __restrict__ b2,     // [8] f32
    const int*  __restrict__ nidx,    // [NPIX][9] i32
    float* __restrict__ outp)         // [16][8][NPIX] f32
{
  __shared__ f16 lds_i[8][16 * 24];            // per-wave scratch: intermediate [b][m]
  __shared__ f16 lds_h[8][16 * 72];            // per-wave scratch: h [b][j]
  __shared__ __align__(16) float stage[128 * 36];  // out tile [(b*8+f)][32 px], stride 36

  const int t = threadIdx.x;
  const int wv = t >> 6;          // 0..7
  const int l = t & 63;
  const int col = l & 15;
  const int q = l >> 4;

  const int bid = blockIdx.x;                         // [0, 512)
  const int slab = ((bid & 7) << 6) + (bid >> 3);     // bijective on [0,512)
  const int p0 = slab << 5;                           // block's 32-pixel base
  const int pw0 = p0 + wv * 4;                        // wave's 4-pixel base

  f16* li = lds_i[wv];
  f16* lh = lds_h[wv];

  const int n0 = (q & 1) * 8;
  const int kh = q >> 1;

  // ---- wave-uniform preloads ----
  int nb[4][9];   // neighbor indices -> SGPRs via readfirstlane
  #pragma unroll
  for (int px = 0; px < 4; ++px)
    #pragma unroll
    for (int k = 0; k < 9; ++k)
      nb[px][k] = __builtin_amdgcn_readfirstlane(nidx[(pw0 + px) * 9 + k]);

  half8 w1f[4];
  float b1f[4];
  #pragma unroll
  for (int jc = 0; jc < 4; ++jc) {
    w1f[jc] = (half8){0, 0, 0, 0, 0, 0, 0, 0};
    if (q < 3) w1f[jc] = cvt8(w1 + (jc * 16 + col) * 24 + q * 8);
    b1f[jc] = b1[jc * 16 + col];
  }
  half8 w2f[2] = {{0, 0, 0, 0, 0, 0, 0, 0}, {0, 0, 0, 0, 0, 0, 0, 0}};
  float b2f = 0.f;
  if (col < 8) {
    w2f[0] = cvt8(w2 + col * 64 + q * 8);
    w2f[1] = cvt8(w2 + col * 64 + 32 + q * 8);
    b2f = b2[col];
  }

  half8 n2f[4];
  #pragma unroll
  for (int px = 0; px < 4; ++px) {
    n2f[px] = (half8){0, 0, 0, 0, 0, 0, 0, 0};
    if (q == 2) n2f[px] = cvt8(noise2 + (col * NPIX + pw0 + px) * 8);
  }

  const f32x4 zero4 = {0.f, 0.f, 0.f, 0.f};

  // unroll 2: pixel i+1's global loads overlap pixel i's MFMA/LDS chains,
  // without blowing past the 128-VGPR cap of (512,4).
  #pragma unroll 2
  for (int px = 0; px < 4; ++px) {
    const int p = pw0 + px;

    // ---- einsum: hoist all 10 fragments, then 5 MFMAs ----
    half8 af[5], bfr[5];
    #pragma unroll
    for (int c = 0; c < 4; ++c) {
      const int k = 2 * c + kh;
      af[c]  = *(const half8*)(feats + nb[px][k] * 256 + col * 16 + n0);
      bfr[c] = cvt8_nt(wmap + ((p * 9 + k) * 16 + col) * 16 + n0);
    }
    af[4]  = (half8){0, 0, 0, 0, 0, 0, 0, 0};
    bfr[4] = (half8){0, 0, 0, 0, 0, 0, 0, 0};
    if (q < 2) {  // kk 128..143 (k=8); 144..159 zero pad
      af[4]  = *(const half8*)(feats + nb[px][8] * 256 + col * 16 + n0);
      bfr[4] = cvt8_nt(wmap + ((p * 9 + 8) * 16 + col) * 16 + n0);
    }
    f32x4 acc = zero4;
    #pragma unroll
    for (int c = 0; c < 5; ++c)
      acc = __builtin_amdgcn_mfma_f32_16x16x32_f16(af[c], bfr[c], acc, 0, 0, 0);

    // intermediate D[b=q*4+r][m=col] -> wave-private LDS (same-wave order, no barrier)
    #pragma unroll
    for (int r = 0; r < 4; ++r)
      li[(q * 4 + r) * 24 + col] = (f16)acc[r];

    // ---- MLP1: K=24 pad 32, N=64 ----
    half8 amlp = n2f[px];                                      // q==2: noise2; q==3: zero
    if (q < 2) amlp = *(const half8*)(li + col * 24 + q * 8);  // d 0..15: intermediate

    #pragma unroll
    for (int jc = 0; jc < 4; ++jc) {
      f32x4 h4 = __builtin_amdgcn_mfma_f32_16x16x32_f16(amlp, w1f[jc], zero4, 0, 0, 0);
      #pragma unroll
      for (int r = 0; r < 4; ++r) {
        float hv = fmaxf(h4[r] + b1f[jc], 0.f);
        lh[(q * 4 + r) * 72 + jc * 16 + col] = (f16)hv;
      }
    }

    // ---- MLP2: K=64, N=8 pad 16 ----
    f32x4 oacc = zero4;
    #pragma unroll
    for (int c2 = 0; c2 < 2; ++c2) {
      half8 a2 = *(const half8*)(lh + col * 72 + c2 * 32 + q * 8);
      oacc = __builtin_amdgcn_mfma_f32_16x16x32_f16(a2, w2f[c2], oacc, 0, 0, 0);
    }
    // stage out[(b*8+f)][px_local] in LDS (f32)
    if (col < 8) {
      const int pxl = wv * 4 + px;
      #pragma unroll
      for (int r = 0; r < 4; ++r) {
        const int row = q * 32 + r * 8 + col;   // b*8 + f
        stage[row * 36 + pxl] = oacc[r] + b2f;
      }
    }
  }

  __syncthreads();

  // ---- cooperative write-out: 128 rows x 32 px, full 128B lines ----
  #pragma unroll
  for (int rr = 0; rr < 2; ++rr) {
    const int idx = rr * 512 + t;
    const int row = idx >> 3;        // (b*8+f)
    const int c8 = idx & 7;          // 8 lanes cover 32 px = one full line
    f32x4 v = *(const f32x4*)&stage[row * 36 + c8 * 4];
    *(f32x4*)(outp + row * NPIX + p0 + c8 * 4) = v;
  }
}

extern "C" void kernel_launch(void* const* d_in, const int* in_sizes, int n_in,
                              void* d_out, int out_size, void* d_ws, size_t ws_size,
                              hipStream_t stream) {
  const float* y    = (const float*)d_in[0];
  const float* nz   = (const float*)d_in[1];
  const float* nz2  = (const float*)d_in[2];
  const float* wmap = (const float*)d_in[3];
  const float* w1   = (const float*)d_in[4];
  const float* b1   = (const float*)d_in[5];
  const float* w2   = (const float*)d_in[6];
  const float* b2   = (const float*)d_in[7];
  const int* nidx   = (const int*)d_in[8];
  float* outp = (float*)d_out;
  f16* feats  = (f16*)d_ws;   // 8 MB scratch: feats[NPIX][16][16] f16

  hipLaunchKernelGGL(pack_feats, dim3(NPIX / 64), dim3(256), 0, stream,
                     y, nz, feats);
  hipLaunchKernelGGL(lr_main, dim3(NPIX / 32), dim3(512), 0, stream,
                     feats, wmap, nz2, w1, b1, w2, b2, nidx, outp);
}

// Round 8
// 252.449 us; speedup vs baseline: 1.1595x; 1.0369x over previous
//
#include <hip/hip_runtime.h>

#define NPIX 16384

typedef _Float16 f16;
typedef __attribute__((ext_vector_type(8))) _Float16 half8;
typedef __attribute__((ext_vector_type(8))) unsigned short ushort8;
typedef __attribute__((ext_vector_type(4))) float f32x4;   // native vec4

// Load 8 consecutive floats (nontemporal), convert to half8 fragment.
__device__ inline half8 cvt8_nt(const float* __restrict__ p) {
  f32x4 a = __builtin_nontemporal_load((const f32x4*)p);
  f32x4 b = __builtin_nontemporal_load((const f32x4*)p + 1);
  half8 r;
  r[0] = (f16)a.x; r[1] = (f16)a.y; r[2] = (f16)a.z; r[3] = (f16)a.w;
  r[4] = (f16)b.x; r[5] = (f16)b.y; r[6] = (f16)b.z; r[7] = (f16)b.w;
  return r;
}
__device__ inline half8 cvt8(const float* __restrict__ p) {
  f32x4 a = *(const f32x4*)p;
  f32x4 b = *(const f32x4*)(p + 4);
  half8 r;
  r[0] = (f16)a.x; r[1] = (f16)a.y; r[2] = (f16)a.z; r[3] = (f16)a.w;
  r[4] = (f16)b.x; r[5] = (f16)b.y; r[6] = (f16)b.z; r[7] = (f16)b.w;
  return r;
}

// Transpose+convert: y [16][8][NPIX] f32 + noise [16][8][NPIX] f32
//   -> feats[p][b][n] f16 ([NPIX][256], 8 MB in d_ws)
__global__ __launch_bounds__(256) void pack_feats(
    const float* __restrict__ y,
    const float* __restrict__ nz,
    f16* __restrict__ out)
{
  __shared__ f16 tile[64][258];
  const int p0 = blockIdx.x << 6;
  const int t = threadIdx.x;
  const int lane16 = t & 15;
  const int pl0 = t >> 4;
  #pragma unroll
  for (int g = 0; g < 16; ++g) {
    const int plane = g * 16 + pl0;          // plane = b*16 + n
    const int b = plane >> 4, n = plane & 15;
    const float* src = (n < 8) ? (y + (b * 8 + n) * NPIX)
                               : (nz + (b * 8 + (n - 8)) * NPIX);
    f32x4 v = __builtin_nontemporal_load((const f32x4*)(src + p0 + lane16 * 4));
    tile[lane16 * 4 + 0][plane] = (f16)v.x;
    tile[lane16 * 4 + 1][plane] = (f16)v.y;
    tile[lane16 * 4 + 2][plane] = (f16)v.z;
    tile[lane16 * 4 + 3][plane] = (f16)v.w;
  }
  __syncthreads();
  #pragma unroll
  for (int it = 0; it < 8; ++it) {
    const int idx = it * 256 + t;
    const int px = idx >> 5;
    const int c = idx & 31;
    ushort8 v = *(const ushort8*)&tile[px][c * 8];
    *(ushort8*)(out + (p0 + px) * 256 + c * 8) = v;  // cached: re-read by lr_einsum
  }
}

// Phase A: einsum only. One wave per pixel, no LDS, lean registers -> high
// occupancy, short wave lifetime, max loads-in-flight for the 151MB wmap stream.
// Writes inter[p][b*16+m] f16 -- exactly the A-fragment layout phase B loads.
// einsum: D[b][m] = sum_{k,n} feats[b][nb(p,k)][n] * wmap[p][k][m][n]  (K=144 pad 160)
// MFMA f32_16x16x32_f16: A[i=lane&15][k=q*8+j], B[j=lane&15][k], D: col=lane&15, row=q*4+r.
__global__ __launch_bounds__(256, 4) void lr_einsum(
    const f16*  __restrict__ feats,   // [NPIX][16][16] f16 (ws)
    const float* __restrict__ wmap,   // [NPIX][9][16][16] f32
    const int*  __restrict__ nidx,    // [NPIX][9] i32
    f16* __restrict__ inter)          // [NPIX][16*16] f16 (ws)
{
  const int t = threadIdx.x;
  const int wv = t >> 6;
  const int l = t & 63;
  const int col = l & 15;
  const int q = l >> 4;

  const int bid = blockIdx.x;                              // [0, 4096)
  const int p = ((((bid & 7) << 9) + (bid >> 3)) << 2) + wv;  // XCD-slab swizzle

  const int n0 = (q & 1) * 8;
  const int kh = q >> 1;

  const int ps = __builtin_amdgcn_readfirstlane(p);
  int nb[9];
  #pragma unroll
  for (int k = 0; k < 9; ++k)
    nb[k] = __builtin_amdgcn_readfirstlane(nidx[ps * 9 + k]);

  half8 af[5], bfr[5];
  #pragma unroll
  for (int c = 0; c < 4; ++c) {
    const int k = 2 * c + kh;
    af[c]  = *(const half8*)(feats + nb[k] * 256 + col * 16 + n0);   // L2-hot gather
    bfr[c] = cvt8_nt(wmap + ((ps * 9 + k) * 16 + col) * 16 + n0);    // streaming, nt
  }
  af[4]  = (half8){0, 0, 0, 0, 0, 0, 0, 0};
  bfr[4] = (half8){0, 0, 0, 0, 0, 0, 0, 0};
  if (q < 2) {  // kk 128..143 (k=8); 144..159 zero pad
    af[4]  = *(const half8*)(feats + nb[8] * 256 + col * 16 + n0);
    bfr[4] = cvt8_nt(wmap + ((ps * 9 + 8) * 16 + col) * 16 + n0);
  }
  f32x4 acc = {0.f, 0.f, 0.f, 0.f};
  #pragma unroll
  for (int c = 0; c < 5; ++c)
    acc = __builtin_amdgcn_mfma_f32_16x16x32_f16(af[c], bfr[c], acc, 0, 0, 0);

  // D[b=q*4+r][m=col] -> inter[p][b*16+m]; 16 lanes x 2B contiguous per (q,r) row.
  #pragma unroll
  for (int r = 0; r < 4; ++r)
    inter[p * 256 + (q * 4 + r) * 16 + col] = (f16)acc[r];
}

// Phase B: MLP. 8 waves/block, 4 px/wave -> 32 consecutive px/block; grid 512.
// mlp_in[b][d]: d0..15 = inter (coalesced half8), d16..23 = noise2, d24..31 = 0.
__global__ __launch_bounds__(512) void lr_mlp(
    const f16*  __restrict__ inter,   // [NPIX][256] f16 (ws)
    const float* __restrict__ noise2, // [16][NPIX][8] f32
    const float* __restrict__ w1,     // [64][24] f32
    const float* __restrict__ b1,     // [64] f32
    const float* __restrict__ w2,     // [8][64] f32
    const float* __restrict__ b2,     // [8] f32
    float* __restrict__ outp)         // [16][8][NPIX] f32
{
  __shared__ f16 lds_h[8][16 * 72];                 // per-wave scratch: h [b][j]
  __shared__ __align__(16) float stage[128 * 36];   // out tile [(b*8+f)][32 px]

  const int t = threadIdx.x;
  const int wv = t >> 6;          // 0..7
  const int l = t & 63;
  const int col = l & 15;
  const int q = l >> 4;

  const int bid = blockIdx.x;                         // [0, 512)
  const int slab = ((bid & 7) << 6) + (bid >> 3);     // bijective on [0,512)
  const int p0 = slab << 5;                           // block's 32-pixel base
  const int pw0 = p0 + wv * 4;                        // wave's 4-pixel base

  f16* lh = lds_h[wv];

  // ---- preloads ----
  half8 w1f[4];
  float b1f[4];
  #pragma unroll
  for (int jc = 0; jc < 4; ++jc) {
    w1f[jc] = (half8){0, 0, 0, 0, 0, 0, 0, 0};
    if (q < 3) w1f[jc] = cvt8(w1 + (jc * 16 + col) * 24 + q * 8);
    b1f[jc] = b1[jc * 16 + col];
  }
  half8 w2f[2] = {{0, 0, 0, 0, 0, 0, 0, 0}, {0, 0, 0, 0, 0, 0, 0, 0}};
  float b2f = 0.f;
  if (col < 8) {
    w2f[0] = cvt8(w2 + col * 64 + q * 8);
    w2f[1] = cvt8(w2 + col * 64 + 32 + q * 8);
    b2f = b2[col];
  }
  half8 n2f[4];
  #pragma unroll
  for (int px = 0; px < 4; ++px) {
    n2f[px] = (half8){0, 0, 0, 0, 0, 0, 0, 0};
    if (q == 2) n2f[px] = cvt8(noise2 + (col * NPIX + pw0 + px) * 8);
  }

  const f32x4 zero4 = {0.f, 0.f, 0.f, 0.f};

  #pragma unroll
  for (int px = 0; px < 4; ++px) {
    const int p = pw0 + px;

    // ---- MLP1: K=24 pad 32, N=64 ----
    half8 amlp = n2f[px];                                   // q==2: noise2; q==3: zero
    if (q < 2) amlp = *(const half8*)(inter + p * 256 + col * 16 + q * 8);  // d0..15

    #pragma unroll
    for (int jc = 0; jc < 4; ++jc) {
      f32x4 h4 = __builtin_amdgcn_mfma_f32_16x16x32_f16(amlp, w1f[jc], zero4, 0, 0, 0);
      #pragma unroll
      for (int r = 0; r < 4; ++r) {
        float hv = fmaxf(h4[r] + b1f[jc], 0.f);
        lh[(q * 4 + r) * 72 + jc * 16 + col] = (f16)hv;     // wave-private, no barrier
      }
    }

    // ---- MLP2: K=64, N=8 pad 16 ----
    f32x4 oacc = zero4;
    #pragma unroll
    for (int c2 = 0; c2 < 2; ++c2) {
      half8 a2 = *(const half8*)(lh + col * 72 + c2 * 32 + q * 8);
      oacc = __builtin_amdgcn_mfma_f32_16x16x32_f16(a2, w2f[c2], oacc, 0, 0, 0);
    }
    if (col < 8) {
      const int pxl = wv * 4 + px;
      #pragma unroll
      for (int r = 0; r < 4; ++r) {
        const int row = q * 32 + r * 8 + col;   // b*8 + f
        stage[row * 36 + pxl] = oacc[r] + b2f;
      }
    }
  }

  __syncthreads();

  // ---- cooperative write-out: 128 rows x 32 px, full 128B lines ----
  #pragma unroll
  for (int rr = 0; rr < 2; ++rr) {
    const int idx = rr * 512 + t;
    const int row = idx >> 3;        // (b*8+f)
    const int c8 = idx & 7;          // 8 lanes cover 32 px = one full line
    f32x4 v = *(const f32x4*)&stage[row * 36 + c8 * 4];
    *(f32x4*)(outp + row * NPIX + p0 + c8 * 4) = v;
  }
}

extern "C" void kernel_launch(void* const* d_in, const int* in_sizes, int n_in,
                              void* d_out, int out_size, void* d_ws, size_t ws_size,
                              hipStream_t stream) {
  const float* y    = (const float*)d_in[0];
  const float* nz   = (const float*)d_in[1];
  const float* nz2  = (const float*)d_in[2];
  const float* wmap = (const float*)d_in[3];
  const float* w1   = (const float*)d_in[4];
  const float* b1   = (const float*)d_in[5];
  const float* w2   = (const float*)d_in[6];
  const float* b2   = (const float*)d_in[7];
  const int* nidx   = (const int*)d_in[8];
  float* outp = (float*)d_out;
  f16* feats = (f16*)d_ws;                                        // 8 MB
  f16* inter = (f16*)((char*)d_ws + (size_t)NPIX * 256 * 2);      // 8 MB

  hipLaunchKernelGGL(pack_feats, dim3(NPIX / 64), dim3(256), 0, stream,
                     y, nz, feats);
  hipLaunchKernelGGL(lr_einsum, dim3(NPIX / 4), dim3(256), 0, stream,
                     feats, wmap, nidx, inter);
  hipLaunchKernelGGL(lr_mlp, dim3(NPIX / 32), dim3(512), 0, stream,
                     inter, nz2, w1, b1, w2, b2, outp);
}